// Round 1
// baseline (98.973 us; speedup 1.0000x reference)
//
#include <hip/hip_runtime.h>

// DirectTuckerNet forward: out[i, k*J + j] = sum_{p,q} M[i,p,q] * C[k,p] * B[j,q]
// with M = (A @ G).reshape(I, R3, R2).  I=J=K=512, R1=R2=R3=4.
//
// Factorization per output row (i,k):
//   W[c]  = sum_r A[i,r] * G[r,c]          (c = p*4+q; once per thread, i uniform per block)
//   v[q]  = sum_p C[k,p] * W[p*4+q]        (per row)
//   out[i,k,j] = sum_q v[q] * B[j,q]       (4 FMA per element)
//
// Block = 256 threads = 32 j-lanes x 8 row-slots. Each thread: 8 rows x 16 j's.
// B rows for the thread's 16 j's live in registers (64 VGPRs), loaded once.
// Grid = 512*512 rows / 64 rows-per-block = 4096 blocks.

#define J_DIM 512

__global__ __launch_bounds__(256) void tucker_fwd(
    const float* __restrict__ A, const float* __restrict__ B,
    const float* __restrict__ C, const float* __restrict__ G,
    float* __restrict__ out)
{
    const int tid = threadIdx.x;
    const int jlane = tid & 31;      // 32 j-lanes cover 512 j's (16 j each)
    const int rslot = tid >> 5;      // 8 row-slots x 8 rows = 64 rows per block
    const int rowBase = blockIdx.x * 64;
    const int i = rowBase >> 9;      // uniform across the block (64 | 512)

    // Load this thread's 16 B rows (j = s*128 + jlane*4 + e) into registers.
    const float4* B4 = reinterpret_cast<const float4*>(B);
    float4 b[4][4];
#pragma unroll
    for (int s = 0; s < 4; ++s) {
        const int j0 = s * 128 + jlane * 4;
#pragma unroll
        for (int e = 0; e < 4; ++e) b[s][e] = B4[j0 + e];
    }

    // W = row i of A@G (16 values), c = p*4 + q  (G is (4,16) row-major)
    const float4 a = reinterpret_cast<const float4*>(A)[i];
    float W[16];
#pragma unroll
    for (int c = 0; c < 16; ++c)
        W[c] = a.x * G[c] + a.y * G[16 + c] + a.z * G[32 + c] + a.w * G[48 + c];

    const float4* C4 = reinterpret_cast<const float4*>(C);
#pragma unroll
    for (int rr = 0; rr < 8; ++rr) {
        const int row = rowBase + rslot * 8 + rr;   // row = i*512 + k
        const int k = row & 511;
        const float4 ck = C4[k];
        const float v0 = ck.x * W[0] + ck.y * W[4] + ck.z * W[8]  + ck.w * W[12];
        const float v1 = ck.x * W[1] + ck.y * W[5] + ck.z * W[9]  + ck.w * W[13];
        const float v2 = ck.x * W[2] + ck.y * W[6] + ck.z * W[10] + ck.w * W[14];
        const float v3 = ck.x * W[3] + ck.y * W[7] + ck.z * W[11] + ck.w * W[15];

        float4* orow = reinterpret_cast<float4*>(out + (size_t)row * J_DIM);
#pragma unroll
        for (int s = 0; s < 4; ++s) {
            float4 o;
            o.x = v0 * b[s][0].x + v1 * b[s][0].y + v2 * b[s][0].z + v3 * b[s][0].w;
            o.y = v0 * b[s][1].x + v1 * b[s][1].y + v2 * b[s][1].z + v3 * b[s][1].w;
            o.z = v0 * b[s][2].x + v1 * b[s][2].y + v2 * b[s][2].z + v3 * b[s][2].w;
            o.w = v0 * b[s][3].x + v1 * b[s][3].y + v2 * b[s][3].z + v3 * b[s][3].w;
            orow[s * 32 + jlane] = o;   // 32 lanes x 16B = 512B contiguous per store
        }
    }
}

extern "C" void kernel_launch(void* const* d_in, const int* in_sizes, int n_in,
                              void* d_out, int out_size, void* d_ws, size_t ws_size,
                              hipStream_t stream) {
    const float* A = (const float*)d_in[0];   // (512, 4)
    const float* B = (const float*)d_in[1];   // (512, 4)
    const float* C = (const float*)d_in[2];   // (512, 4)
    const float* G = (const float*)d_in[3];   // (4, 16)
    float* out = (float*)d_out;               // (512, 512*512) f32

    tucker_fwd<<<4096, 256, 0, stream>>>(A, B, C, G, out);
}

// Round 3
// 97.680 us; speedup vs baseline: 1.0132x; 1.0132x over previous
//
#include <hip/hip_runtime.h>

// DirectTuckerNet forward: out[i, k*J + j] = sum_{p,q} M[i,p,q] * C[k,p] * B[j,q]
// with M = (A @ G).reshape(I, R3, R2).  I=J=K=512, R1=R2=R3=4.
//
// Factorization per output row (i,k):
//   W[c]  = sum_r A[i,r] * G[r,c]          (c = p*4+q; once per thread, i uniform per block)
//   v[q]  = sum_p C[k,p] * W[p*4+q]        (per row)
//   out[i,k,j] = sum_q v[q] * B[j,q]       (4 FMA per element)
//
// Block = 512 threads = 32 j-lanes x 16 row-slots. Each thread: 8 rows x 16 j's.
// B rows for the thread's 16 j's live in registers, loaded once.
// Stores are non-temporal (nt): 512 MB of pure-streaming output with zero reuse
// should not allocate in L2 (output is 16x aggregate L2 capacity).
// Grid = 512*512 rows / 128 rows-per-block = 2048 blocks.

#define J_DIM 512

typedef float f32x4 __attribute__((ext_vector_type(4)));

__global__ __launch_bounds__(512) void tucker_fwd(
    const float* __restrict__ A, const float* __restrict__ B,
    const float* __restrict__ C, const float* __restrict__ G,
    float* __restrict__ out)
{
    const int tid = threadIdx.x;
    const int jlane = tid & 31;      // 32 j-lanes cover 512 j's (16 j each)
    const int rslot = tid >> 5;      // 16 row-slots x 8 rows = 128 rows per block
    const int rowBase = blockIdx.x * 128;
    const int i = rowBase >> 9;      // uniform across the block (128 | 512)

    // Load this thread's 16 B rows (j = s*128 + jlane*4 + e) into registers.
    const float4* B4 = reinterpret_cast<const float4*>(B);
    float4 b[4][4];
#pragma unroll
    for (int s = 0; s < 4; ++s) {
        const int j0 = s * 128 + jlane * 4;
#pragma unroll
        for (int e = 0; e < 4; ++e) b[s][e] = B4[j0 + e];
    }

    // W = row i of A@G (16 values), c = p*4 + q  (G is (4,16) row-major)
    const float4 a = reinterpret_cast<const float4*>(A)[i];
    float W[16];
#pragma unroll
    for (int c = 0; c < 16; ++c)
        W[c] = a.x * G[c] + a.y * G[16 + c] + a.z * G[32 + c] + a.w * G[48 + c];

    const float4* C4 = reinterpret_cast<const float4*>(C);
#pragma unroll
    for (int rr = 0; rr < 8; ++rr) {
        const int row = rowBase + rslot * 8 + rr;   // row = i*512 + k
        const int k = row & 511;
        const float4 ck = C4[k];
        const float v0 = ck.x * W[0] + ck.y * W[4] + ck.z * W[8]  + ck.w * W[12];
        const float v1 = ck.x * W[1] + ck.y * W[5] + ck.z * W[9]  + ck.w * W[13];
        const float v2 = ck.x * W[2] + ck.y * W[6] + ck.z * W[10] + ck.w * W[14];
        const float v3 = ck.x * W[3] + ck.y * W[7] + ck.z * W[11] + ck.w * W[15];

        f32x4* orow = reinterpret_cast<f32x4*>(out + (size_t)row * J_DIM);
#pragma unroll
        for (int s = 0; s < 4; ++s) {
            f32x4 o;
            o.x = v0 * b[s][0].x + v1 * b[s][0].y + v2 * b[s][0].z + v3 * b[s][0].w;
            o.y = v0 * b[s][1].x + v1 * b[s][1].y + v2 * b[s][1].z + v3 * b[s][1].w;
            o.z = v0 * b[s][2].x + v1 * b[s][2].y + v2 * b[s][2].z + v3 * b[s][2].w;
            o.w = v0 * b[s][3].x + v1 * b[s][3].y + v2 * b[s][3].z + v3 * b[s][3].w;
            __builtin_nontemporal_store(o, &orow[s * 32 + jlane]);  // 512B/wave-segment, nt
        }
    }
}

extern "C" void kernel_launch(void* const* d_in, const int* in_sizes, int n_in,
                              void* d_out, int out_size, void* d_ws, size_t ws_size,
                              hipStream_t stream) {
    const float* A = (const float*)d_in[0];   // (512, 4)
    const float* B = (const float*)d_in[1];   // (512, 4)
    const float* C = (const float*)d_in[2];   // (512, 4)
    const float* G = (const float*)d_in[3];   // (4, 16)
    float* out = (float*)d_out;               // (512, 512*512) f32

    tucker_fwd<<<2048, 512, 0, stream>>>(A, B, C, G, out);
}

// Round 4
// 96.040 us; speedup vs baseline: 1.0305x; 1.0171x over previous
//
#include <hip/hip_runtime.h>

// DirectTuckerNet forward: out[i, k*J + j] = sum_{p,q} M[i,p,q] * C[k,p] * B[j,q]
// with M = (A @ G).reshape(I, R3, R2).  I=J=K=512, R1=R2=R3=4.
//
// Factorization per output row (i,k):
//   W[c]  = sum_r A[i,r] * G[r,c]          (once per thread, i uniform per block)
//   v[q]  = sum_p C[k,p] * W[p*4+q]        (per row)
//   out[i,k,j] = sum_q v[q] * B[j,q]       (4 FMA per element)
//
// Block = 256 threads = 32 j-lanes x 8 row-slots; each thread 16 rows x 16 j's.
// 2048 blocks x 4 waves = 8192 waves, 64KB of NT stores per wave — deep
// store-per-wave ratio amortizes the per-block prologue (B/G/A loads, W) and
// halves the wave-dispatch ramp vs the previous 16384-wave launch.

#define J_DIM 512

typedef float f32x4 __attribute__((ext_vector_type(4)));

__global__ __launch_bounds__(256) void tucker_fwd(
    const float* __restrict__ A, const float* __restrict__ B,
    const float* __restrict__ C, const float* __restrict__ G,
    float* __restrict__ out)
{
    const int tid = threadIdx.x;
    const int jlane = tid & 31;      // 32 j-lanes cover 512 j's (16 j each)
    const int rslot = tid >> 5;      // 8 row-slots x 16 rows = 128 rows per block
    const int rowBase = blockIdx.x * 128;
    const int i = rowBase >> 9;      // uniform across the block (128 | 512)

    // Load this thread's 16 B rows (j = s*128 + jlane*4 + e) into registers.
    const float4* B4 = reinterpret_cast<const float4*>(B);
    float4 b[4][4];
#pragma unroll
    for (int s = 0; s < 4; ++s) {
        const int j0 = s * 128 + jlane * 4;
#pragma unroll
        for (int e = 0; e < 4; ++e) b[s][e] = B4[j0 + e];
    }

    // W = row i of A@G (16 values), c = p*4 + q  (G is (4,16) row-major)
    const float4 a = reinterpret_cast<const float4*>(A)[i];
    float W[16];
#pragma unroll
    for (int c = 0; c < 16; ++c)
        W[c] = a.x * G[c] + a.y * G[16 + c] + a.z * G[32 + c] + a.w * G[48 + c];

    const float4* C4 = reinterpret_cast<const float4*>(C);
    const int row0 = rowBase + rslot * 16;
    f32x4* orow = reinterpret_cast<f32x4*>(out + (size_t)row0 * J_DIM);

#pragma unroll 4
    for (int rr = 0; rr < 16; ++rr) {
        const int k = (row0 + rr) & 511;
        const float4 ck = C4[k];
        const float v0 = ck.x * W[0] + ck.y * W[4] + ck.z * W[8]  + ck.w * W[12];
        const float v1 = ck.x * W[1] + ck.y * W[5] + ck.z * W[9]  + ck.w * W[13];
        const float v2 = ck.x * W[2] + ck.y * W[6] + ck.z * W[10] + ck.w * W[14];
        const float v3 = ck.x * W[3] + ck.y * W[7] + ck.z * W[11] + ck.w * W[15];

#pragma unroll
        for (int s = 0; s < 4; ++s) {
            f32x4 o;
            o.x = v0 * b[s][0].x + v1 * b[s][0].y + v2 * b[s][0].z + v3 * b[s][0].w;
            o.y = v0 * b[s][1].x + v1 * b[s][1].y + v2 * b[s][1].z + v3 * b[s][1].w;
            o.z = v0 * b[s][2].x + v1 * b[s][2].y + v2 * b[s][2].z + v3 * b[s][2].w;
            o.w = v0 * b[s][3].x + v1 * b[s][3].y + v2 * b[s][3].z + v3 * b[s][3].w;
            __builtin_nontemporal_store(o, &orow[(size_t)rr * 128 + s * 32 + jlane]);
        }
    }
}

extern "C" void kernel_launch(void* const* d_in, const int* in_sizes, int n_in,
                              void* d_out, int out_size, void* d_ws, size_t ws_size,
                              hipStream_t stream) {
    const float* A = (const float*)d_in[0];   // (512, 4)
    const float* B = (const float*)d_in[1];   // (512, 4)
    const float* C = (const float*)d_in[2];   // (512, 4)
    const float* G = (const float*)d_in[3];   // (4, 16)
    float* out = (float*)d_out;               // (512, 512*512) f32

    tucker_fwd<<<2048, 256, 0, stream>>>(A, B, C, G, out);
}